// Round 7
// baseline (1449.748 us; speedup 1.0000x reference)
//
#include <hip/hip_runtime.h>

#define BT 16
#define NN 8192
#define FIN 128
#define FOUT 32
#define ITILE 512    // i-columns per block
#define KSP 256      // k-rows per block (32 z-splits)
#define NSTEP 16     // KSP / 16

typedef __attribute__((ext_vector_type(8))) short short8;
typedef __attribute__((ext_vector_type(4))) float float4v;

__device__ __forceinline__ float bf2f(unsigned short u) {
    unsigned v = ((unsigned)u) << 16;
    float f;
    __builtin_memcpy(&f, &v, 4);
    return f;
}
__device__ __forceinline__ unsigned short f2bf(float f) {
    unsigned u;
    __builtin_memcpy(&u, &f, 4);
    u += 0x7FFFu + ((u >> 16) & 1u);   // RNE
    return (unsigned short)(u >> 16);
}

// async global->LDS, 16 B per lane; LDS dest = wave-uniform base + lane*16
__device__ __forceinline__ void load_lds16(const unsigned short* g, unsigned short* l) {
    __builtin_amdgcn_global_load_lds((const __attribute__((address_space(1))) void*)g,
                                     (__attribute__((address_space(3))) void*)l, 16, 0, 0);
}

// ---------------------------------------------------------------------------
// Sniff bf16-vs-fp32 (proven R1/R2) + zero sumh[512].
// ---------------------------------------------------------------------------
__global__ void sniff_dtype(const unsigned* __restrict__ Wraw, unsigned* __restrict__ flag,
                            float* __restrict__ sumh) {
    int lane = threadIdx.x;
    unsigned u = Wraw[lane];
    float f = bf2f((unsigned short)(u & 0xFFFFu));
    float af = fabsf(f);
    bool plaus = (af > 1e-5f) && (af < 1e3f);
    unsigned long long msk = __ballot(plaus);
    if (lane == 0) flag[0] = (__popcll(msk) >= 32) ? 1u : 0u;
#pragma unroll
    for (int r = 0; r < 8; ++r) sumh[lane + 64 * r] = 0.f;
}

// ---------------------------------------------------------------------------
// K1: [0,128) zero s2 | [128,1152) h = inp @ W  (+ per-bt column sums of h)
// h now stored NATURAL layout: H[(bt*NN + j)*32 + o] (o contiguous) for the
// D-formulation k2 (A-operand wants o along K) and contiguous k3 reads.
// ---------------------------------------------------------------------------
__launch_bounds__(256)
__global__ void k1(const void* __restrict__ inp_raw, const void* __restrict__ W_raw,
                   unsigned short* __restrict__ H, float* __restrict__ sumh,
                   float4* __restrict__ s2v, const unsigned* __restrict__ flagp) {
    __shared__ __align__(16) unsigned short Wt[32 * 136];
    int bid = blockIdx.x;
    const int tid = threadIdx.x;

    if (bid < 128) {                 // ---- zero s2 (131072 floats = 32768 float4)
        float4 z; z.x = z.y = z.z = z.w = 0.f;
        s2v[bid * 256 + tid] = z;
        return;
    }
    bid -= 128;                      // ---- h-part (R2 k1 body, proven)
    const int bt = bid >> 6;
    const int j0 = (bid & 63) * 128;
    const bool isbf = (*flagp != 0u);

    if (isbf) {
        const unsigned short* Wb = (const unsigned short*)W_raw;
#pragma unroll
        for (int r = 0; r < 16; ++r) {
            int idx = tid + 256 * r, i = idx >> 5, o = idx & 31;
            Wt[o * 136 + i] = Wb[idx];
        }
    } else {
        const float* Wf = (const float*)W_raw;
#pragma unroll
        for (int r = 0; r < 16; ++r) {
            int idx = tid + 256 * r, i = idx >> 5, o = idx & 31;
            Wt[o * 136 + i] = f2bf(Wf[idx]);
        }
    }
    __syncthreads();

    const int lane = tid & 63, w = tid >> 6;
    const int m = lane & 15, q = lane >> 4;
    const int mt = (w & 1) * 16;
    const int nt = (w >> 1) * 64;

    float4v acc[4];
#pragma unroll
    for (int c = 0; c < 4; ++c) { float4v z = {0.f, 0.f, 0.f, 0.f}; acc[c] = z; }

#pragma unroll
    for (int kstep = 0; kstep < 4; ++kstep) {
        short8 af = *(const short8*)&Wt[(mt + m) * 136 + kstep * 32 + q * 8];
#pragma unroll
        for (int c = 0; c < 4; ++c) {
            int j = j0 + nt + c * 16 + m;
            short8 bfrag;
            if (isbf) {
                bfrag = *(const short8*)((const unsigned short*)inp_raw +
                        ((size_t)bt * NN + j) * FIN + kstep * 32 + q * 8);
            } else {
                const float* fp = (const float*)inp_raw + ((size_t)bt * NN + j) * FIN + kstep * 32 + q * 8;
                float4 f0 = *(const float4*)fp;
                float4 f1 = *(const float4*)(fp + 4);
                union { unsigned short u[8]; short8 v; } t;
                t.u[0] = f2bf(f0.x); t.u[1] = f2bf(f0.y); t.u[2] = f2bf(f0.z); t.u[3] = f2bf(f0.w);
                t.u[4] = f2bf(f1.x); t.u[5] = f2bf(f1.y); t.u[6] = f2bf(f1.z); t.u[7] = f2bf(f1.w);
                bfrag = t.v;
            }
            acc[c] = __builtin_amdgcn_mfma_f32_16x16x32_bf16(af, bfrag, acc[c], 0, 0, 0);
        }
    }

    // C-write: natural layout, 4 contiguous o per (c) -> ushort4
#pragma unroll
    for (int c = 0; c < 4; ++c) {
        int j = j0 + nt + c * 16 + m;
        ushort4 p;
        p.x = f2bf(acc[c][0]); p.y = f2bf(acc[c][1]);
        p.z = f2bf(acc[c][2]); p.w = f2bf(acc[c][3]);
        *(ushort4*)&H[((size_t)bt * NN + j) * FOUT + mt + q * 4] = p;
    }
#pragma unroll
    for (int e = 0; e < 4; ++e) {
        float s = acc[0][e] + acc[1][e] + acc[2][e] + acc[3][e];
        s += __shfl_xor(s, 1); s += __shfl_xor(s, 2);
        s += __shfl_xor(s, 4); s += __shfl_xor(s, 8);
        if (m == 0) atomicAdd(&sumh[bt * FOUT + mt + q * 4 + e], s);
    }
}

// ---------------------------------------------------------------------------
// K2 D-form: s2[bt,i] += sum_k mask[k,i] * (h[bt,k,:] . a2[i,:])
// Block: i-tile 512 x k-range 256, 1024 threads (16 waves), 2 blocks/CU.
// Prologue: ballot-pack adj k-range x i-tile (2-KB row spans, read once
// chip-wide) into Pl bits. a2 frags (B-operand, K=o=32) loaded once to regs.
// Loop (16 steps of k16): stage h[all bt][k16][o32]=16KB via pre-swizzled
// global_load_lds (wave w stages bt=w); per wave: 16 bt x 2 i-subtiles:
// D = mfma(h_frag, a2_frag, 0); s2acc[bt][s] += mask_f[e]*D[e].
// No nbr matrix, no Ht re-staging -> the 1.07 GB staging term is GONE.
// ---------------------------------------------------------------------------
__launch_bounds__(1024, 8)
__global__ void k2_fused(const int* __restrict__ adj, const unsigned short* __restrict__ H,
                         const void* __restrict__ a_raw, float* __restrict__ s2,
                         const unsigned* __restrict__ flagp) {
    __shared__ int Pl[KSP * 16];                             // 16 KB mask bits
    __shared__ __align__(16) unsigned short Hs[16 * 512];    // 16 KB h-stage
    const int tid = threadIdx.x;
    const int lane = tid & 63;
    const int w = tid >> 6;              // wave 0..15; owns i-subtiles w*2, w*2+1
    const int m = lane & 15, q = lane >> 4;

    const int bid = blockIdx.x;
    const int ib = bid & 15;             // i-tile
    const int z = bid >> 4;              // k-split 0..31
    const int i0 = ib * ITILE;
    const int k0 = z * KSP;

    // ---- prologue: ballot-pack adj rows [k0, k0+256) x cols [i0, i0+512)
    // wave w owns 16 rows; per row 8 ballot rounds of 64 cols.
    {
        const size_t kb = (size_t)(k0 + w * 16);
        for (int lr = 0; lr < 16; lr += 2) {
            int v[16];
#pragma unroll
            for (int j = 0; j < 16; ++j) {
                int row = lr + (j >> 3), c = j & 7;
                v[j] = adj[(kb + row) * NN + i0 + c * 64 + lane];
            }
#pragma unroll
            for (int j = 0; j < 16; ++j) {
                unsigned long long b = __ballot(v[j] > 0);
                if (lane == 0) {
                    int row = w * 16 + lr + (j >> 3), c = j & 7;
                    int2 t;
                    t.x = (int)(unsigned)(b & 0xFFFFFFFFull);
                    t.y = (int)(unsigned)(b >> 32);
                    *(int2*)&Pl[row * 16 + c * 2] = t;
                }
            }
        }
    }

    // ---- a2 B-frags (once): sub s: col i = i0+(w*2+s)*16+m, o-elems q*8..+7
    const bool isbf = (*flagp != 0u);
    short8 a2f[2];
#pragma unroll
    for (int s = 0; s < 2; ++s) {
        int gi = i0 + (w * 2 + s) * 16 + m;
        union { unsigned short u[8]; short8 v; } t;
        if (isbf) {
            const unsigned short* ab = (const unsigned short*)a_raw;
#pragma unroll
            for (int tt = 0; tt < 8; ++tt)
                t.u[tt] = ab[(size_t)(FOUT + q * 8 + tt) * NN + gi];
        } else {
            const float* afp = (const float*)a_raw;
#pragma unroll
            for (int tt = 0; tt < 8; ++tt)
                t.u[tt] = f2bf(afp[(size_t)(FOUT + q * 8 + tt) * NN + gi]);
        }
        a2f[s] = t.v;
    }

    // h-stage swizzle: LDS slot s holds h(row s>>2, oct (s&3)^((s>>4)&3)).
    // source offset (halfwords) for this lane's 16-B DMA chunk:
    const int soff = ((lane >> 2) * 32) + (((lane & 3) ^ ((lane >> 4) & 3)) * 8);
    // read slot for A-frag: lane(m,q) -> slot m*4 + (q ^ ((m>>2)&3))
    const int rsl = (m * 4 + (q ^ ((m >> 2) & 3))) * 8;

    float s2acc[16][2];
#pragma unroll
    for (int bt = 0; bt < 16; ++bt) { s2acc[bt][0] = 0.f; s2acc[bt][1] = 0.f; }

    __syncthreads();     // Pl complete

    for (int st = 0; st < NSTEP; ++st) {
        // ---- stage h[bt=w][k16][o32] (1 KB contiguous) via swizzled DMA
        load_lds16(H + ((size_t)w * NN + k0 + st * 16) * 32 + soff, &Hs[w * 512]);
        // ---- mask floats for this k16: rows q*4+e, word w, bits s*16+m
        float mskf[2][4];
#pragma unroll
        for (int e = 0; e < 4; ++e) {
            unsigned wrd = (unsigned)Pl[(st * 16 + q * 4 + e) * 16 + w];
            mskf[0][e] = ((wrd >> m) & 1u) ? 1.f : 0.f;
            mskf[1][e] = ((wrd >> (16 + m)) & 1u) ? 1.f : 0.f;
        }
        __syncthreads();     // Hs ready
#pragma unroll
        for (int bt = 0; bt < 16; ++bt) {
            short8 af = *(const short8*)&Hs[bt * 512 + rsl];
#pragma unroll
            for (int s = 0; s < 2; ++s) {
                float4v D = {0.f, 0.f, 0.f, 0.f};
                D = __builtin_amdgcn_mfma_f32_16x16x32_bf16(af, a2f[s], D, 0, 0, 0);
#pragma unroll
                for (int e = 0; e < 4; ++e)
                    s2acc[bt][s] = fmaf(mskf[s][e], D[e], s2acc[bt][s]);
            }
        }
        __syncthreads();     // compute done before next stage overwrites
    }

    // ---- epilogue: reduce q-partials, atomicAdd (32 z-splits accumulate)
#pragma unroll
    for (int bt = 0; bt < 16; ++bt) {
#pragma unroll
        for (int s = 0; s < 2; ++s) {
            float v = s2acc[bt][s];
            v += __shfl_xor(v, 16);
            v += __shfl_xor(v, 32);
            if (q == 0)
                atomicAdd(&s2[(size_t)bt * NN + i0 + (w * 2 + s) * 16 + m], v);
        }
    }
}

// ---------------------------------------------------------------------------
// K3: s = s2 + sum_o h*a1 ; out = relu(s * sumh[bt,:])  (h natural layout)
// ---------------------------------------------------------------------------
__launch_bounds__(256)
__global__ void k3_out(const unsigned short* __restrict__ H, const float* __restrict__ s2,
                       const float* __restrict__ sumh, const void* __restrict__ a_raw,
                       void* __restrict__ out_raw, const unsigned* __restrict__ flagp) {
    const int i = blockIdx.x * 256 + threadIdx.x;
    const int bt = blockIdx.y;
    const bool isbf = (*flagp != 0u);

    float s = s2[(size_t)bt * NN + i];
    const unsigned short* hp = H + ((size_t)bt * NN + i) * FOUT;
    if (isbf) {
        const unsigned short* ab = (const unsigned short*)a_raw;
#pragma unroll
        for (int ob = 0; ob < 4; ++ob) {
            short8 hv = *(const short8*)(hp + ob * 8);
#pragma unroll
            for (int t = 0; t < 8; ++t) {
                int o = ob * 8 + t;
                s += bf2f((unsigned short)hv[t]) * bf2f(ab[(size_t)o * NN + i]);
            }
        }
    } else {
        const float* afp = (const float*)a_raw;
#pragma unroll
        for (int ob = 0; ob < 4; ++ob) {
            short8 hv = *(const short8*)(hp + ob * 8);
#pragma unroll
            for (int t = 0; t < 8; ++t) {
                int o = ob * 8 + t;
                s += bf2f((unsigned short)hv[t]) * afp[(size_t)o * NN + i];
            }
        }
    }

    float ov[32];
#pragma unroll
    for (int o = 0; o < 32; ++o) ov[o] = fmaxf(s * sumh[bt * FOUT + o], 0.f);

    size_t ob2 = ((size_t)bt * NN + i) * FOUT;
    if (isbf) {
        unsigned short* o16 = (unsigned short*)out_raw + ob2;
#pragma unroll
        for (int c = 0; c < 8; ++c) {
            ushort4 p;
            p.x = f2bf(ov[c * 4 + 0]); p.y = f2bf(ov[c * 4 + 1]);
            p.z = f2bf(ov[c * 4 + 2]); p.w = f2bf(ov[c * 4 + 3]);
            *(ushort4*)(o16 + c * 4) = p;
        }
    } else {
        float* of = (float*)out_raw + ob2;
#pragma unroll
        for (int c = 0; c < 8; ++c) {
            float4 v;
            v.x = ov[c * 4 + 0]; v.y = ov[c * 4 + 1]; v.z = ov[c * 4 + 2]; v.w = ov[c * 4 + 3];
            *(float4*)(of + c * 4) = v;
        }
    }
}

// ---------------------------------------------------------------------------
extern "C" void kernel_launch(void* const* d_in, const int* in_sizes, int n_in,
                              void* d_out, int out_size, void* d_ws, size_t ws_size,
                              hipStream_t stream) {
    const void* inp = d_in[0];
    const int* adj = (const int*)d_in[1];
    const void* W = d_in[2];
    const void* a = d_in[3];

    char* ws = (char*)d_ws;
    unsigned short* H = (unsigned short*)ws;                     // 8 MB
    unsigned* flag = (unsigned*)(ws + 8388608);                  // 4 B
    float* s2 = (float*)(ws + 8388608 + 4096);                   // 512 KB (16B aligned)
    float* sumh = (float*)(ws + 8388608 + 4096 + 524288);        // 2 KB

    sniff_dtype<<<1, 64, 0, stream>>>((const unsigned*)W, flag, sumh);
    k1<<<1152, 256, 0, stream>>>(inp, W, H, sumh, (float4*)s2, flag);
    k2_fused<<<512, 1024, 0, stream>>>(adj, H, a, s2, flag);
    k3_out<<<dim3(NN / 256, BT), 256, 0, stream>>>(H, s2, sumh, a, d_out, flag);
}

// Round 8
// 556.958 us; speedup vs baseline: 2.6030x; 2.6030x over previous
//
#include <hip/hip_runtime.h>

#define BT 16
#define NN 8192
#define FIN 128
#define FOUT 32
#define NB 512       // BT*FOUT
#define SPLITK 4
#define KSPAN (NN / SPLITK)   // 2048

typedef __attribute__((ext_vector_type(8))) short short8;
typedef __attribute__((ext_vector_type(4))) float float4v;

__device__ __forceinline__ float bf2f(unsigned short u) {
    unsigned v = ((unsigned)u) << 16;
    float f;
    __builtin_memcpy(&f, &v, 4);
    return f;
}
__device__ __forceinline__ unsigned short f2bf(float f) {
    unsigned u;
    __builtin_memcpy(&u, &f, 4);
    u += 0x7FFFu + ((u >> 16) & 1u);   // RNE
    return (unsigned short)(u >> 16);
}

// ---------------------------------------------------------------------------
// Sniff bf16-vs-fp32 (proven R1/R2) + zero sumh[512].
// ---------------------------------------------------------------------------
__global__ void sniff_dtype(const unsigned* __restrict__ Wraw, unsigned* __restrict__ flag,
                            float* __restrict__ sumh) {
    int lane = threadIdx.x;
    unsigned u = Wraw[lane];
    float f = bf2f((unsigned short)(u & 0xFFFFu));
    float af = fabsf(f);
    bool plaus = (af > 1e-5f) && (af < 1e3f);
    unsigned long long msk = __ballot(plaus);
    if (lane == 0) flag[0] = (__popcll(msk) >= 32) ? 1u : 0u;
#pragma unroll
    for (int r = 0; r < 8; ++r) sumh[lane + 64 * r] = 0.f;
}

// ---------------------------------------------------------------------------
// K1: [0,128) zero s2 | [128,1152) h = inp @ W  (+ per-bt column sums of h)
// Ht layout (R1-proven): Ht[(bt*FOUT + o)*NN + j]
// ---------------------------------------------------------------------------
__launch_bounds__(256)
__global__ void k1(const void* __restrict__ inp_raw, const void* __restrict__ W_raw,
                   unsigned short* __restrict__ Ht, float* __restrict__ sumh,
                   float4* __restrict__ s2v, const unsigned* __restrict__ flagp) {
    __shared__ __align__(16) unsigned short Wt[32 * 136];
    int bid = blockIdx.x;
    const int tid = threadIdx.x;

    if (bid < 128) {                 // ---- zero s2 (131072 floats = 32768 float4)
        float4 z; z.x = z.y = z.z = z.w = 0.f;
        s2v[bid * 256 + tid] = z;
        return;
    }
    bid -= 128;                      // ---- h-part (R2 k1 body, proven)
    const int bt = bid >> 6;
    const int j0 = (bid & 63) * 128;
    const bool isbf = (*flagp != 0u);

    if (isbf) {
        const unsigned short* Wb = (const unsigned short*)W_raw;
#pragma unroll
        for (int r = 0; r < 16; ++r) {
            int idx = tid + 256 * r, i = idx >> 5, o = idx & 31;
            Wt[o * 136 + i] = Wb[idx];
        }
    } else {
        const float* Wf = (const float*)W_raw;
#pragma unroll
        for (int r = 0; r < 16; ++r) {
            int idx = tid + 256 * r, i = idx >> 5, o = idx & 31;
            Wt[o * 136 + i] = f2bf(Wf[idx]);
        }
    }
    __syncthreads();

    const int lane = tid & 63, w = tid >> 6;
    const int m = lane & 15, q = lane >> 4;
    const int mt = (w & 1) * 16;
    const int nt = (w >> 1) * 64;

    float4v acc[4];
#pragma unroll
    for (int c = 0; c < 4; ++c) { float4v z = {0.f, 0.f, 0.f, 0.f}; acc[c] = z; }

#pragma unroll
    for (int kstep = 0; kstep < 4; ++kstep) {
        short8 af = *(const short8*)&Wt[(mt + m) * 136 + kstep * 32 + q * 8];
#pragma unroll
        for (int c = 0; c < 4; ++c) {
            int j = j0 + nt + c * 16 + m;
            short8 bfrag;
            if (isbf) {
                bfrag = *(const short8*)((const unsigned short*)inp_raw +
                        ((size_t)bt * NN + j) * FIN + kstep * 32 + q * 8);
            } else {
                const float* fp = (const float*)inp_raw + ((size_t)bt * NN + j) * FIN + kstep * 32 + q * 8;
                float4 f0 = *(const float4*)fp;
                float4 f1 = *(const float4*)(fp + 4);
                union { unsigned short u[8]; short8 v; } t;
                t.u[0] = f2bf(f0.x); t.u[1] = f2bf(f0.y); t.u[2] = f2bf(f0.z); t.u[3] = f2bf(f0.w);
                t.u[4] = f2bf(f1.x); t.u[5] = f2bf(f1.y); t.u[6] = f2bf(f1.z); t.u[7] = f2bf(f1.w);
                bfrag = t.v;
            }
            acc[c] = __builtin_amdgcn_mfma_f32_16x16x32_bf16(af, bfrag, acc[c], 0, 0, 0);
        }
    }

#pragma unroll
    for (int c = 0; c < 4; ++c) {
#pragma unroll
        for (int e = 0; e < 4; ++e) {
            int o = mt + q * 4 + e;
            int j = j0 + nt + c * 16 + m;
            Ht[(size_t)(bt * FOUT + o) * NN + j] = f2bf(acc[c][e]);
        }
    }
#pragma unroll
    for (int e = 0; e < 4; ++e) {
        float s = acc[0][e] + acc[1][e] + acc[2][e] + acc[3][e];
        s += __shfl_xor(s, 1); s += __shfl_xor(s, 2);
        s += __shfl_xor(s, 4); s += __shfl_xor(s, 8);
        if (m == 0) atomicAdd(&sumh[bt * FOUT + mt + q * 4 + e], s);
    }
}

// ---------------------------------------------------------------------------
// K2: s2[bt][i] += sum_o a2[i,o] * (sum_k (adj[k][i]>0) * Ht[bt*32+o][k])
// R8 structure: NO B-staging, NO loop barriers.
//  - Prologue: per-thread pack of the block's 64-col x 2048-row adj slice into
//    a padded col-major LDS bitmask (16.6 KB). adj loads NONTEMPORAL so the
//    256 MB stream doesn't evict the L2-resident Ht slice. One syncthreads.
//  - K-loop (64 x K=32): A-frags expanded in-register from bitmask words
//    (broadcast LDS read + ~12 VALU per frag); B-frags read DIRECTLY from
//    global Ht (L2-resident 2 MB z-slice via XCD swizzle). Waves run free;
//    compiler software-pipelines (auto vmcnt, no lockstep drains).
// ---------------------------------------------------------------------------
__launch_bounds__(512, 4)
__global__ void k2_fused(const int* __restrict__ adj, const unsigned short* __restrict__ Ht,
                         const void* __restrict__ a_raw, float* __restrict__ s2,
                         const unsigned* __restrict__ flagp) {
    __shared__ int Pl[64 * 65];          // 16.6 KB col-major bitmask, pad 65
    const int tid = threadIdx.x;
    const int lane = tid & 63;
    const int w = tid >> 6;              // wave 0..7, owns n in [w*64, w*64+64)
    const int m = lane & 15, q = lane >> 4;
    const int wn = w * 64;

    // XCD-aware decomposition: bid&7 ~ XCD; 2 XCDs per z-slice -> each XCD's
    // 2 MB Ht k-slice stays resident in its private L2.
    const int bid = blockIdx.x;
    const int xcd = bid & 7;
    const int z = xcd >> 1;                          // 0..3
    const int ib = (bid >> 3) | ((xcd & 1) << 6);    // 0..127 (bijective)
    const int i0 = ib * 64;
    const int zbase = z * KSPAN;

    // ---- prologue: pack adj bits. thread = column i0+lane, wave w = rows
    // [w*256, w*256+256) of the z-slice. 8 words of 32 rows each.
    {
        const int* arow = adj + (size_t)(zbase + w * 256) * NN + i0 + lane;
#pragma unroll
        for (int u = 0; u < 8; ++u) {
            unsigned wv = 0;
            const int* gp = arow + (size_t)(u * 32) * NN;
#pragma unroll
            for (int j = 0; j < 32; ++j)
                wv |= (__builtin_nontemporal_load(gp + (size_t)j * NN) > 0 ? 1u : 0u) << j;
            Pl[lane * 65 + w * 8 + u] = (int)wv;
        }
    }
    __syncthreads();     // Pl complete — the ONLY barrier

    // B pointers: row n = wn + c*16 + m, k-start = zbase + q*8
    const unsigned short* bp[4];
#pragma unroll
    for (int c = 0; c < 4; ++c)
        bp[c] = Ht + (size_t)(wn + c * 16 + m) * NN + zbase + q * 8;

    float4v acc[4][4];
#pragma unroll
    for (int r = 0; r < 4; ++r)
#pragma unroll
        for (int c = 0; c < 4; ++c) { float4v zz = {0.f, 0.f, 0.f, 0.f}; acc[r][c] = zz; }

#pragma unroll 4
    for (int t = 0; t < 64; ++t) {
        // B-frags direct from L2 (16 rows x 64 B contiguous per instr)
        short8 bfr[4];
#pragma unroll
        for (int c = 0; c < 4; ++c)
            bfr[c] = *(const short8*)(bp[c] + t * 32);
        // A-frags from bitmask: word t of column r*16+m, bits q*8..q*8+7
        short8 af[4];
#pragma unroll
        for (int r = 0; r < 4; ++r) {
            unsigned word = (unsigned)Pl[(r * 16 + m) * 65 + t];
            unsigned byt = (word >> (q * 8)) & 0xFFu;
            union { unsigned d[4]; short8 v; } tt;
            tt.d[0] = (byt & 1u   ? 0x3F80u : 0u) | (byt & 2u   ? 0x3F800000u : 0u);
            tt.d[1] = (byt & 4u   ? 0x3F80u : 0u) | (byt & 8u   ? 0x3F800000u : 0u);
            tt.d[2] = (byt & 16u  ? 0x3F80u : 0u) | (byt & 32u  ? 0x3F800000u : 0u);
            tt.d[3] = (byt & 64u  ? 0x3F80u : 0u) | (byt & 128u ? 0x3F800000u : 0u);
            af[r] = tt.v;
        }
#pragma unroll
        for (int c = 0; c < 4; ++c)
#pragma unroll
            for (int r = 0; r < 4; ++r)
                acc[r][c] = __builtin_amdgcn_mfma_f32_16x16x32_bf16(af[r], bfr[c], acc[r][c], 0, 0, 0);
    }

    // ---- fused epilogue: s2 partial = sum_o nbr*a2, m-lane reduce, atomic
    const bool isbf = (*flagp != 0u);
    const int btA = wn >> 5;                  // = 2*w
#pragma unroll
    for (int r = 0; r < 4; ++r) {
#pragma unroll
        for (int e = 0; e < 4; ++e) {
            int gi = i0 + r * 16 + q * 4 + e;
            float a2m, a2m16;
            if (isbf) {
                const unsigned short* ab = (const unsigned short*)a_raw;
                a2m   = bf2f(ab[(size_t)(FOUT + m) * NN + gi]);
                a2m16 = bf2f(ab[(size_t)(FOUT + 16 + m) * NN + gi]);
            } else {
                const float* afp = (const float*)a_raw;
                a2m   = afp[(size_t)(FOUT + m) * NN + gi];
                a2m16 = afp[(size_t)(FOUT + 16 + m) * NN + gi];
            }
            float sA = acc[r][0][e] * a2m + acc[r][1][e] * a2m16;
            float sB = acc[r][2][e] * a2m + acc[r][3][e] * a2m16;
            sA += __shfl_xor(sA, 1); sA += __shfl_xor(sA, 2);
            sA += __shfl_xor(sA, 4); sA += __shfl_xor(sA, 8);
            sB += __shfl_xor(sB, 1); sB += __shfl_xor(sB, 2);
            sB += __shfl_xor(sB, 4); sB += __shfl_xor(sB, 8);
            if (m == 0) {
                atomicAdd(&s2[(size_t)btA * NN + gi], sA);
                atomicAdd(&s2[(size_t)(btA + 1) * NN + gi], sB);
            }
        }
    }
}

// ---------------------------------------------------------------------------
// K3: s = s2 + sum_o h*a1 ; out = relu(s * sumh[bt,:])
// ---------------------------------------------------------------------------
__launch_bounds__(256)
__global__ void k3_out(const unsigned short* __restrict__ Ht, const float* __restrict__ s2,
                       const float* __restrict__ sumh, const void* __restrict__ a_raw,
                       void* __restrict__ out_raw, const unsigned* __restrict__ flagp) {
    const int i = blockIdx.x * 256 + threadIdx.x;
    const int bt = blockIdx.y;
    const bool isbf = (*flagp != 0u);

    float s = s2[(size_t)bt * NN + i];
    if (isbf) {
        const unsigned short* ab = (const unsigned short*)a_raw;
#pragma unroll
        for (int o = 0; o < 32; ++o) {
            float h = bf2f(Ht[(size_t)(bt * FOUT + o) * NN + i]);
            s += h * bf2f(ab[(size_t)o * NN + i]);
        }
    } else {
        const float* afp = (const float*)a_raw;
#pragma unroll
        for (int o = 0; o < 32; ++o) {
            float h = bf2f(Ht[(size_t)(bt * FOUT + o) * NN + i]);
            s += h * afp[(size_t)o * NN + i];
        }
    }

    float ov[32];
#pragma unroll
    for (int o = 0; o < 32; ++o) ov[o] = fmaxf(s * sumh[bt * FOUT + o], 0.f);

    size_t ob = ((size_t)bt * NN + i) * FOUT;
    if (isbf) {
        unsigned short* o16 = (unsigned short*)out_raw + ob;
#pragma unroll
        for (int c = 0; c < 8; ++c) {
            ushort4 p;
            p.x = f2bf(ov[c * 4 + 0]); p.y = f2bf(ov[c * 4 + 1]);
            p.z = f2bf(ov[c * 4 + 2]); p.w = f2bf(ov[c * 4 + 3]);
            *(ushort4*)(o16 + c * 4) = p;
        }
    } else {
        float* of = (float*)out_raw + ob;
#pragma unroll
        for (int c = 0; c < 8; ++c) {
            float4 v;
            v.x = ov[c * 4 + 0]; v.y = ov[c * 4 + 1]; v.z = ov[c * 4 + 2]; v.w = ov[c * 4 + 3];
            *(float4*)(of + c * 4) = v;
        }
    }
}

// ---------------------------------------------------------------------------
extern "C" void kernel_launch(void* const* d_in, const int* in_sizes, int n_in,
                              void* d_out, int out_size, void* d_ws, size_t ws_size,
                              hipStream_t stream) {
    const void* inp = d_in[0];
    const int* adj = (const int*)d_in[1];
    const void* W = d_in[2];
    const void* a = d_in[3];

    char* ws = (char*)d_ws;
    unsigned short* Ht = (unsigned short*)ws;                    // 8 MB
    unsigned* flag = (unsigned*)(ws + 8388608);                  // 4 B
    float* s2 = (float*)(ws + 8388608 + 4096);                   // 512 KB (16B aligned)
    float* sumh = (float*)(ws + 8388608 + 4096 + 524288);        // 2 KB

    sniff_dtype<<<1, 64, 0, stream>>>((const unsigned*)W, flag, sumh);
    k1<<<1152, 256, 0, stream>>>(inp, W, Ht, sumh, (float4*)s2, flag);
    k2_fused<<<512, 512, 0, stream>>>(adj, Ht, a, s2, flag);
    k3_out<<<dim3(NN / 256, BT), 256, 0, stream>>>(Ht, s2, sumh, a, d_out, flag);
}